// Round 4
// baseline (195.068 us; speedup 1.0000x reference)
//
#include <hip/hip_runtime.h>

#define F_DIM 128
#define TE_DIM 32
#define DD 160
#define NB 4096
#define KK 64

// ws layout (float offsets). Total 1366528 floats = 5.47 MB of d_ws.
#define WS_M    0          // [160][160]  (Wk^T Wq) / sqrt(160)
#define WS_V2   25600      // [160][160]  out_w @ Wv
#define WS_C    51200      // [160]       (Wk^T bq) / sqrt(160)
#define WS_U    51360      // [160]       (Wq^T bk) / sqrt(160)
#define WS_B2   51520      // [160]       out_w @ bv + out_b
#define WS_S0   51680      // [1]         (bq . bk) / sqrt(160)
#define WS_WTOT 51681
#define WS_QT   51712      // [4096][160] q_tilde
#define WS_SBK  707072     // [4096]
#define WS_WKV  711168     // [4096][160]

__device__ __forceinline__ float dot4acc(const float4 w, const float4 v, float a) {
    a = fmaf(w.x, v.x, a);
    a = fmaf(w.y, v.y, a);
    a = fmaf(w.z, v.z, a);
    a = fmaf(w.w, v.w, a);
    return a;
}
__device__ __forceinline__ float wave_max(float v) {
    #pragma unroll
    for (int off = 32; off > 0; off >>= 1) v = fmaxf(v, __shfl_xor(v, off, 64));
    return v;
}
__device__ __forceinline__ float wave_sum(float v) {
    #pragma unroll
    for (int off = 32; off > 0; off >>= 1) v += __shfl_xor(v, off, 64);
    return v;
}

// ---------------- K1: fold weight matrices ----------------
__global__ void setup_kernel(const float* __restrict__ ipw, const float* __restrict__ ipb,
                             const float* __restrict__ ow,  const float* __restrict__ ob,
                             float* __restrict__ ws)
{
    const int g = blockIdx.x * blockDim.x + threadIdx.x;
    const float inv = 0.07905694150420949f;  // 1/sqrt(160)
    if (g < 25600) {
        const int e = g / DD, f = g % DD;
        const float* wk = ipw + DD * DD;
        float a = 0.f;
        for (int d = 0; d < DD; ++d) a = fmaf(wk[d * DD + e], ipw[d * DD + f], a);
        ws[WS_M + g] = a * inv;
    } else if (g < 51200) {
        const int gg = g - 25600;
        const int i = gg / DD, f = gg % DD;
        const float* wv = ipw + 2 * DD * DD;
        float a = 0.f;
        for (int d = 0; d < DD; ++d) a = fmaf(ow[i * DD + d], wv[d * DD + f], a);
        ws[WS_V2 + gg] = a;
    } else if (g < 51360) {
        const int e = g - 51200;
        const float* wk = ipw + DD * DD;
        float a = 0.f;
        for (int d = 0; d < DD; ++d) a = fmaf(wk[d * DD + e], ipb[d], a);
        ws[WS_C + e] = a * inv;
    } else if (g < 51520) {
        const int f = g - 51360;
        float a = 0.f;
        for (int d = 0; d < DD; ++d) a = fmaf(ipw[d * DD + f], ipb[DD + d], a);
        ws[WS_U + f] = a * inv;
    } else if (g < 51680) {
        const int i = g - 51520;
        float a = ob[i];
        for (int d = 0; d < DD; ++d) a = fmaf(ow[i * DD + d], ipb[2 * DD + d], a);
        ws[WS_B2 + i] = a;
    } else if (g == 51680) {
        float a = 0.f;
        for (int d = 0; d < DD; ++d) a = fmaf(ipb[d], ipb[DD + d], a);
        ws[WS_S0] = a * inv;
    }
}

// ---------------- K2: qt = qin @ M^T + C ; sbk = qin.U + s0 ----------------
// 16 rows/block, grid 256. M element read once per block, 16-lane broadcast.
__global__ __launch_bounds__(256)
void qt_kernel(const float* __restrict__ x,
               const int* __restrict__ tni, const int* __restrict__ tnt,
               const float* __restrict__ te_w, const float* __restrict__ te_b,
               float* __restrict__ ws)
{
    __shared__ __attribute__((aligned(16))) float s_qin[16][164]; // 164: 2-way max (free)
    __shared__ int   s_tn[16];
    __shared__ float s_tt[16];
    const int t  = threadIdx.x;
    const int b0 = blockIdx.x * 16;

    if (t < 16) { s_tn[t] = tni[b0 + t]; s_tt[t] = (float)tnt[b0 + t]; }
    __syncthreads();

    // stage qin: thread = (row, 16-float segment)
    {
        const int r = t >> 4, seg = t & 15;
        const float4* src = (const float4*)(x + (long)s_tn[r] * F_DIM + seg * 8);
        const float4 a = src[0], bq = src[1];
        *(float4*)&s_qin[r][seg * 8]     = a;
        *(float4*)&s_qin[r][seg * 8 + 4] = bq;
        const int j2 = seg * 2;
        s_qin[r][F_DIM + j2]     = cosf(s_tt[r] * te_w[j2]     + te_b[j2]);
        s_qin[r][F_DIM + j2 + 1] = cosf(s_tt[r] * te_w[j2 + 1] + te_b[j2 + 1]);
    }
    __syncthreads();

    // sbk
    {
        const int r = t >> 4, seg = t & 15;
        const float* U = ws + WS_U;
        float p = 0.f;
        #pragma unroll
        for (int i = 0; i < 10; ++i) p = fmaf(s_qin[r][seg * 10 + i], U[seg * 10 + i], p);
        #pragma unroll
        for (int off = 1; off < 16; off <<= 1) p += __shfl_xor(p, off, 64);
        if (seg == 0) ws[WS_SBK + b0 + r] = p + ws[WS_S0];
    }

    // qt: thread = (row = t&15, e-group of 10 = t>>4)
    {
        const int r = t & 15, eg = t >> 4;
        const float* M = ws + WS_M;
        const float* C = ws + WS_C;
        float acc[10];
        #pragma unroll
        for (int j = 0; j < 10; ++j) acc[j] = C[eg * 10 + j];
        for (int f0 = 0; f0 < DD; f0 += 8) {
            const float4 q0 = *(const float4*)&s_qin[r][f0];
            const float4 q1 = *(const float4*)&s_qin[r][f0 + 4];
            #pragma unroll
            for (int j = 0; j < 10; ++j) {
                const float4* mp = (const float4*)(M + (long)(eg * 10 + j) * DD + f0);
                acc[j] = dot4acc(mp[0], q0, acc[j]);
                acc[j] = dot4acc(mp[1], q1, acc[j]);
            }
        }
        float* qt = ws + WS_QT + (long)(b0 + r) * DD + eg * 10;
        #pragma unroll
        for (int j = 0; j < 10; ++j) qt[j] = acc[j];
    }
}

// ---------------- K3: scores -> softmax -> mask + wkv ----------------
// Wave per row. P2 reads 2 neighbor rows per instr, coalesced float4.
__global__ __launch_bounds__(256, 4)
void attn_kernel(const float* __restrict__ x,
                 const int* __restrict__ neighbor_ids,
                 const int* __restrict__ edge_time,
                 const float* __restrict__ gumbel_u,
                 const float* __restrict__ te_w, const float* __restrict__ te_b,
                 float* __restrict__ ws,
                 float* __restrict__ out_mask)
{
    __shared__ __attribute__((aligned(4))) _Float16 s_te[4][KK][36];
    __shared__ int   s_nid[4][KK];
    __shared__ float s_sc[4][KK];
    __shared__ float s_aw[4][KK];
    __shared__ float s_qte[4][TE_DIM];

    const int tid = threadIdx.x, wr = tid >> 6, lane = tid & 63;
    const long b = (long)blockIdx.x * 4 + wr;

    // meta + te table (each cos exactly once; lane = k)
    {
        s_nid[wr][lane] = neighbor_ids[b * KK + lane];
        const float etv = (float)edge_time[b * KK + lane];
        #pragma unroll
        for (int jj = 0; jj < 16; ++jj) {
            union { _Float16 h[2]; unsigned u; } pk;
            pk.h[0] = (_Float16)cosf(etv * te_w[2 * jj]     + te_b[2 * jj]);
            pk.h[1] = (_Float16)cosf(etv * te_w[2 * jj + 1] + te_b[2 * jj + 1]);
            *(unsigned*)&s_te[wr][lane][2 * jj] = pk.u;
        }
    }
    // qt fragment (both halves identical -> requests merge) + qte + sbk
    const int fl = lane & 31, half = lane >> 5;
    const float4 qf = *(const float4*)(ws + WS_QT + b * DD + 4 * fl);
    if (lane < TE_DIM) s_qte[wr][lane] = ws[WS_QT + b * DD + F_DIM + lane];
    const float sbk = ws[WS_SBK + b];

    // tedot for k = lane
    float tedot = 0.f;
    #pragma unroll
    for (int jj = 0; jj < 16; ++jj) {
        union { _Float16 h[2]; unsigned u; } pk;
        pk.u = *(const unsigned*)&s_te[wr][lane][2 * jj];
        tedot = fmaf(s_qte[wr][2 * jj],     (float)pk.h[0], tedot);
        tedot = fmaf(s_qte[wr][2 * jj + 1], (float)pk.h[1], tedot);
    }

    // P2: x-part of scores, 2 k's per iteration, coalesced
    #pragma unroll 4
    for (int i = 0; i < 32; ++i) {
        const int k  = 2 * i + half;
        const int nk = s_nid[wr][k];
        const float4 xv = *(const float4*)(x + (long)nk * F_DIM + 4 * fl);
        float p = 0.f;
        p = dot4acc(xv, qf, p);
        p += __shfl_xor(p, 16, 64);
        p += __shfl_xor(p, 8, 64);
        p += __shfl_xor(p, 4, 64);
        p += __shfl_xor(p, 2, 64);
        p += __shfl_xor(p, 1, 64);
        if (fl == 0) s_sc[wr][k] = p;
    }

    // softmax over k = lane
    float aw;
    {
        const float sc = s_sc[wr][lane] + tedot + sbk;
        const float m = wave_max(sc);
        const float e = expf(sc - m);
        const float l = wave_sum(e);
        aw = e / l;
        s_aw[wr][lane] = aw;
    }

    // gumbel mask
    {
        const float u = gumbel_u[b * KK + lane];
        const float g = -logf(-logf(u + 1e-10f) + 1e-10f);
        const float z = aw + g;  // TAU = 1.0
        const float m = wave_max(z);
        const float e = expf(z - m);
        const float l = wave_sum(e);
        out_mask[b * KK + lane] = (e / l > 0.2f) ? 1.0f : 0.0f;
    }

    // wkv = sum_k aw[k] * kv[k] (lane = feature pair), coalesced
    {
        float ax = 0.f, ay = 0.f, at = 0.f;
        const float* xb = x + lane * 2;
        const int lte = lane & 31;
        #pragma unroll 8
        for (int k = 0; k < KK; ++k) {
            const float wgt = s_aw[wr][k];
            const int   nk  = s_nid[wr][k];
            const float2 xv = *(const float2*)(xb + (long)nk * F_DIM);
            ax = fmaf(wgt, xv.x, ax);
            ay = fmaf(wgt, xv.y, ay);
            at = fmaf(wgt, (float)s_te[wr][k][lte], at);
        }
        float* wkv = ws + WS_WKV + b * DD;
        wkv[lane * 2]     = ax;
        wkv[lane * 2 + 1] = ay;
        if (lane < TE_DIM) wkv[F_DIM + lane] = at;
    }
}

// ---------------- K4: ao = wkv @ V2^T + B2 ; epilogue ----------------
__global__ __launch_bounds__(256)
void ao_kernel(const float* __restrict__ edge_weight,
               const float* __restrict__ mlp_w, const float* __restrict__ mlp_b,
               float* __restrict__ ws,
               float* __restrict__ out_ao, float* __restrict__ out_new)
{
    __shared__ __attribute__((aligned(16))) float s_v[16][164];
    __shared__ __attribute__((aligned(16))) float s_ao[16][164];
    __shared__ float s_base[16];
    const int t  = threadIdx.x;
    const int b0 = blockIdx.x * 16;

    // stage wkv tile (coalesced)
    #pragma unroll
    for (int c = 0; c < 10; ++c) {
        const int idx = t + 256 * c;
        s_v[idx / DD][idx % DD] = ws[WS_WKV + (long)b0 * DD + idx];
    }
    __syncthreads();

    // ao tile
    {
        const int r = t & 15, eg = t >> 4;
        const float* V2 = ws + WS_V2;
        const float* B2 = ws + WS_B2;
        float acc[10];
        #pragma unroll
        for (int j = 0; j < 10; ++j) acc[j] = B2[eg * 10 + j];
        for (int f0 = 0; f0 < DD; f0 += 8) {
            const float4 q0 = *(const float4*)&s_v[r][f0];
            const float4 q1 = *(const float4*)&s_v[r][f0 + 4];
            #pragma unroll
            for (int j = 0; j < 10; ++j) {
                const float4* mp = (const float4*)(V2 + (long)(eg * 10 + j) * DD + f0);
                acc[j] = dot4acc(mp[0], q0, acc[j]);
                acc[j] = dot4acc(mp[1], q1, acc[j]);
            }
        }
        #pragma unroll
        for (int j = 0; j < 10; ++j) s_ao[r][eg * 10 + j] = acc[j];
    }
    __syncthreads();

    // mlp base per row
    {
        const int r = t >> 4, seg = t & 15;
        float p = 0.f;
        #pragma unroll
        for (int i = 0; i < 10; ++i) p = fmaf(s_ao[r][seg * 10 + i], mlp_w[seg * 10 + i], p);
        #pragma unroll
        for (int off = 1; off < 16; off <<= 1) p += __shfl_xor(p, off, 64);
        if (seg == 0) s_base[r] = p + mlp_b[0];
    }
    __syncthreads();

    // stores (coalesced)
    #pragma unroll
    for (int c = 0; c < 10; ++c) {
        const int idx = t + 256 * c;
        out_ao[(long)b0 * DD + idx] = s_ao[idx / DD][idx % DD];
    }
    #pragma unroll
    for (int c = 0; c < 4; ++c) {
        const int idx = t + 256 * c;
        const int r = idx >> 6, kx = idx & 63;
        const float ew  = edge_weight[(long)(b0 + r) * KK + kx];
        const float val = fmaf(ew, mlp_w[DD], s_base[r]);
        out_new[(long)(b0 + r) * KK + kx] = (val >= 0.f) ? val : 0.01f * val;
    }
}

extern "C" void kernel_launch(void* const* d_in, const int* in_sizes, int n_in,
                              void* d_out, int out_size, void* d_ws, size_t ws_size,
                              hipStream_t stream) {
    const float* x   = (const float*)d_in[0];
    const int*   tni = (const int*)d_in[1];
    const int*   tnt = (const int*)d_in[2];
    const int*   nid = (const int*)d_in[3];
    const int*   et  = (const int*)d_in[4];
    const float* ew  = (const float*)d_in[5];
    const float* gu  = (const float*)d_in[6];
    const float* tew = (const float*)d_in[7];
    const float* teb = (const float*)d_in[8];
    const float* ipw = (const float*)d_in[9];
    const float* ipb = (const float*)d_in[10];
    const float* ow  = (const float*)d_in[11];
    const float* ob  = (const float*)d_in[12];
    const float* mw  = (const float*)d_in[13];
    const float* mb  = (const float*)d_in[14];

    float* wsf = (float*)d_ws;

    float* out      = (float*)d_out;
    float* out_ao   = out;
    float* out_new  = out + (long)NB * DD;
    float* out_mask = out + (long)NB * DD + (long)NB * KK;

    setup_kernel<<<(WS_WTOT + 255) / 256, 256, 0, stream>>>(ipw, ipb, ow, ob, wsf);
    qt_kernel<<<NB / 16, 256, 0, stream>>>(x, tni, tnt, tew, teb, wsf);
    attn_kernel<<<NB / 4, 256, 0, stream>>>(x, nid, et, gu, tew, teb, wsf, out_mask);
    ao_kernel<<<NB / 16, 256, 0, stream>>>(ew, mw, mb, wsf, out_ao, out_new);
}